// Round 4
// baseline (531.480 us; speedup 1.0000x reference)
//
#include <hip/hip_runtime.h>
#include <hip/hip_bf16.h>

// InterpretableMultiHeadAttention  B=1, S=384, D=512, H=8, DK=64
// Dtype resolution: inputs fp32 (R1: bf16 reads -> NaN). R3 established
// outputs are fp32 too: the bit-identical 2.82e-3 error across two different
// ws layouts == bf16(attn) pairs read back as fp32 inside chunk 0, i.e. my
// bf16 writes only half-filled an fp32 output buffer. The "(bf16, ref=np)"
// label is a hardcoded literal in the harness, not the out dtype.
//
// Factored algebra (exact):
//   scores_h = 0.125*(q_h (Wq_h Wk_h^T) k_h^T + q_h.uq + k_h.uk + c)
//   hvo_h    = v_h (Wv_s Wo / 8) + pb
//   out[s,t,:] = sum_h attn[h,s,t]*hvo[h,t,:] + bo

#define SS_ 384
#define DD_ 512
#define HH_ 8
#define DKK_ 64

typedef __hip_bfloat16 bf16;

// ---- generic 64x64-tile fp32 GEMM, K multiple of 64, 256 threads ----------
// C[m0+m, n0+n] = scale*(sum_k A[m,k]*B[k,n] + rvec[m] + zvec[n]) + bias[n]
// NT=true: B accessed as B[n, k] (row-major [N,K]).
template <bool NT>
__device__ __forceinline__ void tile64(
    const float* __restrict__ A, int lda,
    const float* __restrict__ B, int ldb,
    const float* __restrict__ bias,
    const float* __restrict__ rvec,
    const float* __restrict__ zvec,
    float scale,
    float* __restrict__ C, int ldc, int K, int m0, int n0)
{
    __shared__ float As[64][65];   // As[m][k]
    __shared__ float Bs[64][65];   // Bs[k][n]
    const int tid = threadIdx.x;
    const int lr = tid >> 2;           // 0..63
    const int lc = (tid & 3) << 4;     // 0,16,32,48
    const int ty = tid >> 4, tx = tid & 15;
    float acc[4][4] = {};

    for (int k0 = 0; k0 < K; k0 += 64) {
        const float* Ap = A + (size_t)(m0 + lr) * lda + (k0 + lc);
#pragma unroll
        for (int u = 0; u < 16; u += 4) {
            float4 t4 = *(const float4*)(Ap + u);
            As[lr][lc + u + 0] = t4.x; As[lr][lc + u + 1] = t4.y;
            As[lr][lc + u + 2] = t4.z; As[lr][lc + u + 3] = t4.w;
        }
        if (!NT) {
            const float* Bp = B + (size_t)(k0 + lr) * ldb + (n0 + lc);
#pragma unroll
            for (int u = 0; u < 16; u += 4) {
                float4 t4 = *(const float4*)(Bp + u);
                Bs[lr][lc + u + 0] = t4.x; Bs[lr][lc + u + 1] = t4.y;
                Bs[lr][lc + u + 2] = t4.z; Bs[lr][lc + u + 3] = t4.w;
            }
        } else {
            const float* Bp = B + (size_t)(n0 + lr) * ldb + (k0 + lc);
#pragma unroll
            for (int u = 0; u < 16; ++u) Bs[lc + u][lr] = Bp[u];
        }
        __syncthreads();
#pragma unroll 16
        for (int kk = 0; kk < 64; ++kk) {
            float a[4], b[4];
#pragma unroll
            for (int i = 0; i < 4; ++i) a[i] = As[(ty << 2) + i][kk];
#pragma unroll
            for (int j = 0; j < 4; ++j) b[j] = Bs[kk][(tx << 2) + j];
#pragma unroll
            for (int i = 0; i < 4; ++i)
#pragma unroll
                for (int j = 0; j < 4; ++j)
                    acc[i][j] = fmaf(a[i], b[j], acc[i][j]);
        }
        __syncthreads();
    }
#pragma unroll
    for (int i = 0; i < 4; ++i) {
        const int m = m0 + (ty << 2) + i;
#pragma unroll
        for (int j = 0; j < 4; ++j) {
            const int n = n0 + (tx << 2) + j;
            float val = acc[i][j];
            if (rvec) val += rvec[m];
            if (zvec) val += zvec[n];
            val *= scale;
            if (bias) val += bias[n];
            C[(size_t)m * ldc + n] = val;
        }
    }
}

// ---- precompute: M_h = Wq_h @ Wk_h^T  (grid 8) -----------------------------
__global__ __launch_bounds__(256) void pcM_kernel(
    const float* __restrict__ Wq_h, const float* __restrict__ Wk_h,
    float* __restrict__ M)
{
    const int h = blockIdx.x;
    tile64<true>(Wq_h + (size_t)h * DKK_ * DD_, DD_,
                 Wk_h + (size_t)h * DKK_ * DD_, DD_,
                 nullptr, nullptr, nullptr, 1.0f,
                 M + (size_t)h * DKK_ * DKK_, DKK_, DD_, 0, 0);
}

// ---- precompute: uq[h,i]=Wq_h[h,i,:]·bk_h[h,:]; uk[h,j]=Wk_h[h,j,:]·bq_h[h,:];
//      c[h]=bq_h[h,:]·bk_h[h,:]   (grid 5 x 256) -----------------------------
__global__ __launch_bounds__(256) void pcUV_kernel(
    const float* __restrict__ Wq_h, const float* __restrict__ bq_h,
    const float* __restrict__ Wk_h, const float* __restrict__ bk_h,
    float* __restrict__ uq, float* __restrict__ uk, float* __restrict__ cc)
{
    const int id = blockIdx.x * 256 + threadIdx.x;
    if (id < 512) {
        const int h = id >> 6, i = id & 63;
        float s = 0.f;
        for (int d = 0; d < DD_; ++d)
            s = fmaf(Wq_h[(size_t)(h * DKK_ + i) * DD_ + d], bk_h[h * DD_ + d], s);
        uq[id] = s;
    } else if (id < 1024) {
        const int t = id - 512, h = t >> 6, j = t & 63;
        float s = 0.f;
        for (int d = 0; d < DD_; ++d)
            s = fmaf(Wk_h[(size_t)(h * DKK_ + j) * DD_ + d], bq_h[h * DD_ + d], s);
        uk[t] = s;
    } else if (id < 1032) {
        const int h = id - 1024;
        float s = 0.f;
        for (int d = 0; d < DD_; ++d)
            s = fmaf(bq_h[h * DD_ + d], bk_h[h * DD_ + d], s);
        cc[h] = s;
    }
}

// ---- precompute: P = (Wv_s @ Wo)/8  [64,512]  (grid 8) ---------------------
__global__ __launch_bounds__(256) void pcP_kernel(
    const float* __restrict__ Wv_s, const float* __restrict__ Wo,
    float* __restrict__ P)
{
    tile64<false>(Wv_s, DD_, Wo, DD_, nullptr, nullptr, nullptr, 0.125f,
                  P, DD_, DD_, 0, blockIdx.x * 64);
}

// ---- precompute: pb[e] = (bv_s·Wo[:,e])/8  (grid 2) ------------------------
__global__ __launch_bounds__(256) void pcPb_kernel(
    const float* __restrict__ bv_s, const float* __restrict__ Wo,
    float* __restrict__ pb)
{
    const int e = blockIdx.x * 256 + threadIdx.x;
    if (e < DD_) {
        float s = 0.f;
        for (int d = 0; d < DD_; ++d)
            s = fmaf(bv_s[d], Wo[(size_t)d * DD_ + e], s);
        pb[e] = 0.125f * s;
    }
}

// ---- qkv = x @ W + b   (grid 8,6,3) ----------------------------------------
__global__ __launch_bounds__(256) void qkv_kernel(
    const float* __restrict__ x,
    const float* __restrict__ Wq, const float* __restrict__ bq,
    const float* __restrict__ Wk, const float* __restrict__ bk,
    const float* __restrict__ Wv, const float* __restrict__ bv,
    float* __restrict__ q, float* __restrict__ k, float* __restrict__ v)
{
    const float *W, *b; float* C;
    if (blockIdx.z == 0)      { W = Wq; b = bq; C = q; }
    else if (blockIdx.z == 1) { W = Wk; b = bk; C = k; }
    else                      { W = Wv; b = bv; C = v; }
    tile64<false>(x, DD_, W, DD_, b, nullptr, nullptr, 1.0f,
                  C, DD_, DD_, blockIdx.y * 64, blockIdx.x * 64);
}

// ---- N[h] = q_h @ M_h   [384,64]  (grid 6,8) -------------------------------
__global__ __launch_bounds__(256) void nK_kernel(
    const float* __restrict__ q, const float* __restrict__ M,
    float* __restrict__ N)
{
    const int h = blockIdx.y;
    tile64<false>(q + h * DKK_, DD_, M + (size_t)h * DKK_ * DKK_, DKK_,
                  nullptr, nullptr, nullptr, 1.0f,
                  N + (size_t)h * SS_ * DKK_, DKK_, DKK_, blockIdx.x * 64, 0);
}

// ---- r[h,s] = q_h[s]·uq_h + c_h ;  z[h,t] = k_h[t]·uk_h   (grid 24) --------
__global__ __launch_bounds__(256) void rz_kernel(
    const float* __restrict__ q, const float* __restrict__ k,
    const float* __restrict__ uq, const float* __restrict__ uk,
    const float* __restrict__ cc,
    float* __restrict__ r, float* __restrict__ z)
{
    const int id = blockIdx.x * 256 + threadIdx.x;
    if (id < HH_ * SS_) {
        const int h = id / SS_, s = id % SS_;
        float acc = cc[h];
        for (int i = 0; i < DKK_; ++i)
            acc = fmaf(q[(size_t)s * DD_ + h * DKK_ + i], uq[h * DKK_ + i], acc);
        r[id] = acc;
    } else if (id < 2 * HH_ * SS_) {
        const int t2 = id - HH_ * SS_;
        const int h = t2 / SS_, t = t2 % SS_;
        float acc = 0.f;
        for (int j = 0; j < DKK_; ++j)
            acc = fmaf(k[(size_t)t * DD_ + h * DKK_ + j], uk[h * DKK_ + j], acc);
        z[t2] = acc;
    }
}

// ---- attn_pre[h] = 0.125*(N_h @ k_h^T + r + z)   (grid 6,6,8) --------------
__global__ __launch_bounds__(256) void scores_kernel(
    const float* __restrict__ N, const float* __restrict__ k,
    const float* __restrict__ r, const float* __restrict__ z,
    float* __restrict__ attn)
{
    const int h = blockIdx.z;
    tile64<true>(N + (size_t)h * SS_ * DKK_, DKK_,
                 k + h * DKK_, DD_,
                 nullptr, r + h * SS_, z + h * SS_, 0.125f,
                 attn + (size_t)h * SS_ * SS_, SS_, DKK_,
                 blockIdx.y * 64, blockIdx.x * 64);
}

// ---- row softmax over t, in place   (grid 3072, block 512) -----------------
__global__ __launch_bounds__(512) void softmax_kernel(float* __restrict__ attn)
{
    __shared__ float red[512];
    float* p = attn + (size_t)blockIdx.x * SS_;
    const int tid = threadIdx.x;
    const float x = (tid < SS_) ? p[tid] : -INFINITY;
    red[tid] = x;
    __syncthreads();
    for (int st = 256; st > 0; st >>= 1) {
        if (tid < st) red[tid] = fmaxf(red[tid], red[tid + st]);
        __syncthreads();
    }
    const float m = red[0];
    __syncthreads();
    const float e = (tid < SS_) ? __expf(x - m) : 0.0f;
    red[tid] = e;
    __syncthreads();
    for (int st = 256; st > 0; st >>= 1) {
        if (tid < st) red[tid] += red[tid + st];
        __syncthreads();
    }
    const float inv = 1.0f / red[0];
    if (tid < SS_) p[tid] = e * inv;
}

// ---- hvo[h] = v_h @ P + pb   [384,512]  (grid 8,6,8) -----------------------
__global__ __launch_bounds__(256) void hvo_kernel(
    const float* __restrict__ v, const float* __restrict__ P,
    const float* __restrict__ pb, float* __restrict__ hvo)
{
    const int h = blockIdx.z;
    tile64<false>(v + h * DKK_, DD_, P, DD_, pb, nullptr, nullptr, 1.0f,
                  hvo + (size_t)h * SS_ * DD_, DD_, DKK_,
                  blockIdx.y * 64, blockIdx.x * 64);
}

// ---- out[s,t,:] = sum_h attn[h,s,t]*hvo[h,t,:] + bo   (grid 384,12) --------
// fp32 output (R3 finding).
__global__ __launch_bounds__(256) void epilogue_kernel(
    const float* __restrict__ attn, const float* __restrict__ hvo,
    const float* __restrict__ bo, float* __restrict__ out)
{
    __shared__ float hvT[HH_][DD_];   // 16 KB
    __shared__ float aT[HH_][32];
    __shared__ float boL[DD_];
    const int t = blockIdx.x;
    const int s0 = blockIdx.y * 32;
    const int tid = threadIdx.x;

#pragma unroll
    for (int i = 0; i < 16; ++i) {
        const int idx = tid + i * 256;
        const int h = idx >> 9, d = idx & 511;
        hvT[h][d] = hvo[((size_t)h * SS_ + t) * DD_ + d];
    }
    boL[tid] = bo[tid];
    boL[tid + 256] = bo[tid + 256];
    {
        const int h = tid >> 5, si = tid & 31;
        aT[h][si] = attn[(size_t)h * SS_ * SS_ + (size_t)(s0 + si) * SS_ + t];
    }
    __syncthreads();

    const int d0 = tid * 2;
    float hv0[HH_], hv1[HH_];
#pragma unroll
    for (int h = 0; h < HH_; ++h) { hv0[h] = hvT[h][d0]; hv1[h] = hvT[h][d0 + 1]; }
    const float b0 = boL[d0], b1 = boL[d0 + 1];

    for (int si = 0; si < 32; ++si) {
        float o0 = b0, o1 = b1;
#pragma unroll
        for (int h = 0; h < HH_; ++h) {
            const float a = aT[h][si];
            o0 = fmaf(a, hv0[h], o0);
            o1 = fmaf(a, hv1[h], o1);
        }
        const size_t off = ((size_t)(s0 + si) * SS_ + t) * DD_ + d0;
        float2 pk; pk.x = o0; pk.y = o1;
        *(float2*)(out + off) = pk;
    }
}

// ---- second output = attn[7] as fp32   (grid 576) --------------------------
__global__ __launch_bounds__(256) void copy_attn_kernel(
    const float* __restrict__ attn7, float* __restrict__ out2)
{
    const int i = blockIdx.x * 256 + threadIdx.x;
    if (i < SS_ * SS_) out2[i] = attn7[i];
}

extern "C" void kernel_launch(void* const* d_in, const int* in_sizes, int n_in,
                              void* d_out, int out_size, void* d_ws, size_t ws_size,
                              hipStream_t stream) {
    const float* x    = (const float*)d_in[0];
    const float* Wq   = (const float*)d_in[1];
    const float* bq   = (const float*)d_in[2];
    const float* Wk   = (const float*)d_in[3];
    const float* bk   = (const float*)d_in[4];
    const float* Wv   = (const float*)d_in[5];
    const float* bv   = (const float*)d_in[6];
    const float* Wq_h = (const float*)d_in[7];
    const float* bq_h = (const float*)d_in[8];
    const float* Wk_h = (const float*)d_in[9];
    const float* bk_h = (const float*)d_in[10];
    const float* Wv_s = (const float*)d_in[11];
    const float* bv_s = (const float*)d_in[12];
    const float* Wo   = (const float*)d_in[13];
    const float* bo   = (const float*)d_in[14];

    const size_t SD  = (size_t)SS_ * DD_;    // 196608
    const size_t SSZ = (size_t)SS_ * SS_;    // 147456
    float* ws = (float*)d_ws;
    float* q    = ws;               ws += SD;
    float* k    = ws;               ws += SD;
    float* v    = ws;               ws += SD;
    float* M    = ws;               ws += (size_t)HH_ * DKK_ * DKK_;  // 32768
    float* uq   = ws;               ws += HH_ * DKK_;                 // 512
    float* uk   = ws;               ws += HH_ * DKK_;                 // 512
    float* cc   = ws;               ws += 32;                         // 8 (padded)
    float* N    = ws;               ws += (size_t)HH_ * SS_ * DKK_;   // 196608
    float* r    = ws;               ws += HH_ * SS_;                  // 3072
    float* z    = ws;               ws += HH_ * SS_;                  // 3072
    float* P    = ws;               ws += (size_t)DKK_ * DD_;         // 32768
    float* pb   = ws;               ws += DD_;                        // 512
    float* attn = ws;               ws += (size_t)HH_ * SSZ;          // 1179648
    float* hvo  = ws;               ws += (size_t)HH_ * SD;           // 1572864
    // total ~3.61M floats = 13.8 MB

    float* out0 = (float*)d_out;                   // [1,384,384,512] fp32
    float* out1 = out0 + (size_t)SS_ * SS_ * DD_;  // [1,384,384] fp32

    pcM_kernel  <<<dim3(HH_),        256, 0, stream>>>(Wq_h, Wk_h, M);
    pcUV_kernel <<<dim3(5),          256, 0, stream>>>(Wq_h, bq_h, Wk_h, bk_h, uq, uk, cc);
    pcP_kernel  <<<dim3(8),          256, 0, stream>>>(Wv_s, Wo, P);
    pcPb_kernel <<<dim3(2),          256, 0, stream>>>(bv_s, Wo, pb);
    qkv_kernel  <<<dim3(8, 6, 3),    256, 0, stream>>>(x, Wq, bq, Wk, bk, Wv, bv, q, k, v);
    nK_kernel   <<<dim3(6, HH_),     256, 0, stream>>>(q, M, N);
    rz_kernel   <<<dim3(24),         256, 0, stream>>>(q, k, uq, uk, cc, r, z);
    scores_kernel<<<dim3(6, 6, HH_), 256, 0, stream>>>(N, k, r, z, attn);
    softmax_kernel<<<dim3(HH_ * SS_),512, 0, stream>>>(attn);
    hvo_kernel  <<<dim3(8, 6, HH_),  256, 0, stream>>>(v, P, pb, hvo);
    epilogue_kernel<<<dim3(SS_, 12), 256, 0, stream>>>(attn, hvo, bo, out0);
    copy_attn_kernel<<<dim3(576),    256, 0, stream>>>(attn + 7 * SSZ, out1);
}